// Round 12
// baseline (256.911 us; speedup 1.0000x reference)
//
#include <hip/hip_runtime.h>

typedef __bf16 bf16x8 __attribute__((ext_vector_type(8)));
typedef float f32x4 __attribute__((ext_vector_type(4)));
typedef float f32x16 __attribute__((ext_vector_type(16)));

__device__ __forceinline__ unsigned short f2bf(float f) {
  union { float f; unsigned u; } v; v.f = f;
  unsigned u = v.u;
  return (unsigned short)((u + 0x7fffu + ((u >> 16) & 1u)) >> 16);  // RNE
}
__device__ __forceinline__ void gload_lds16(const void* g, void* l) {
  __builtin_amdgcn_global_load_lds(
      (const __attribute__((address_space(1))) unsigned int*)g,
      (__attribute__((address_space(3))) unsigned int*)l, 16, 0, 0);
}
__device__ __forceinline__ unsigned cvtpk(float lo, float hi) {
  unsigned r;
  asm("v_cvt_pk_bf16_f32 %0, %1, %2" : "=v"(r) : "v"(lo), "v"(hi));
  return r;
}
// bulk f32->bf16 x4 via hardware cvt_pk (RNE, same rounding as f2bf)
__device__ __forceinline__ void cvt4(const float* __restrict__ s,
                                     unsigned short* __restrict__ d, int u) {
  f32x4 v = ((const f32x4*)s)[u];
  unsigned lo = cvtpk(v[0], v[1]);
  unsigned hi = cvtpk(v[2], v[3]);
  unsigned long long o = ((unsigned long long)hi << 32) | (unsigned long long)lo;
  ((unsigned long long*)d)[u] = o;
}

// LDS tile swizzle (128B rows): row r, 16B-chunk c stored at position c^(r&7).
// Staging lane fetches global chunk (ln&7)^(ln>>3); reads XOR chunk with r&7.
// For 256B rows: chunk c (0..15) at position (c&8)|((c&7)^(r&7)).

// ---------------- prep: f32->bf16 conversions + ebj, one launch -------------
__global__ void prep(const float* __restrict__ x, const float* __restrict__ W1,
                     const float* __restrict__ Wv, const float* __restrict__ Wp,
                     const float* __restrict__ w2, const float* __restrict__ b2,
                     unsigned short* __restrict__ xb, unsigned short* __restrict__ W1b,
                     unsigned short* __restrict__ Wvb, unsigned short* __restrict__ Wpb,
                     unsigned short* __restrict__ w2t, unsigned short* __restrict__ ebj) {
  int u = blockIdx.x * 256 + threadIdx.x;
  if (u < 1048576) { cvt4(x, xb, u); return; }
  u -= 1048576;
  if (u < 262144) { cvt4(W1, W1b, u); return; }
  u -= 262144;
  if (u < 262144) { cvt4(Wv, Wvb, u); return; }
  u -= 262144;
  if (u < 262144) { cvt4(Wp, Wpb, u); return; }
  u -= 262144;
  if (u < 32768) {
    // w2 (64,2048) f32 -> w2t (2048,64) bf16
    int j = u >> 4, d4 = (u & 15) * 4;
    union { unsigned short s[4]; unsigned long long x; } o;
#pragma unroll
    for (int i = 0; i < 4; ++i) o.s[i] = f2bf(w2[(d4 + i) * 2048 + j]);
    ((unsigned long long*)w2t)[u] = o.x;
    return;
  }
  u -= 32768;
  // ebj = bf16(exp(b2)), 2048 elems in 512 x4-units
  union { unsigned short s[4]; unsigned long long x; } o;
#pragma unroll
  for (int i = 0; i < 4; ++i) o.s[i] = f2bf(__expf(b2[u * 4 + i]));
  ((unsigned long long*)ebj)[u] = o.x;
}

// ---------------- fused r & vt GEMM: r3 config (best measured total) --------
// 64x64 tile, 4 waves, 32x32 MFMA, shared-X fragments, simple 2-barrier loop,
// 24KB LDS, grid (64,16)=1024 blocks = 4/CU.
__global__ __launch_bounds__(256) void gemm_rv(
    const unsigned short* __restrict__ xb, const unsigned short* __restrict__ W1b,
    const unsigned short* __restrict__ Wvb, const float* __restrict__ b1,
    const float* __restrict__ bv, const float* __restrict__ b2,
    unsigned short* __restrict__ rb, unsigned short* __restrict__ vtb) {
  __shared__ unsigned short Xs[64 * 64];
  __shared__ unsigned short W1s[64 * 64];
  __shared__ unsigned short Wvs[64 * 64];
  const int tm = blockIdx.x * 64, n0 = blockIdx.y * 64;
  const int tid = threadIdx.x;
  const int wv = tid >> 6, ln = tid & 63;
  const int l5 = ln >> 5, l31 = ln & 31;
  const int tw = (wv & 1) * 32;      // token base within tile
  const int cw = (wv >> 1) * 32;     // chan base within tile
  const int rowL = ln >> 3;
  const int kc = (((ln & 7) ^ rowL) & 7) * 8;

  int xoff[4], woff[4];
#pragma unroll
  for (int kk = 0; kk < 4; ++kk) {
    int c = kk * 2 + l5;
    int p = (c ^ (l31 & 7)) * 8;
    xoff[kk] = (tw + l31) * 64 + p;
    woff[kk] = (cw + l31) * 64 + p;
  }

  f32x16 accR, accV;
#pragma unroll
  for (int i = 0; i < 16; ++i) { accR[i] = 0.f; accV[i] = 0.f; }

  for (int k0 = 0; k0 < 1024; k0 += 64) {
    __syncthreads();
#pragma unroll
    for (int l = 0; l < 2; ++l) {
      int row = l * 32 + wv * 8 + rowL;
      gload_lds16(xb + (tm + row) * 1024 + k0 + kc, &Xs[l * 2048 + wv * 512]);
      gload_lds16(W1b + (n0 + row) * 1024 + k0 + kc, &W1s[l * 2048 + wv * 512]);
      gload_lds16(Wvb + (n0 + row) * 1024 + k0 + kc, &Wvs[l * 2048 + wv * 512]);
    }
    __syncthreads();
#pragma unroll
    for (int kk = 0; kk < 4; ++kk) {
      bf16x8 xa  = *(const bf16x8*)&Xs[xoff[kk]];
      bf16x8 w1f = *(const bf16x8*)&W1s[woff[kk]];
      bf16x8 wvf = *(const bf16x8*)&Wvs[woff[kk]];
      accR = __builtin_amdgcn_mfma_f32_32x32x16_bf16(xa, w1f, accR, 0, 0, 0);
      accV = __builtin_amdgcn_mfma_f32_32x32x16_bf16(wvf, xa, accV, 0, 0, 0);
    }
  }
  {
    int col = n0 + cw + l31;
    float bc = b1[col];
#pragma unroll
    for (int r = 0; r < 16; ++r) {
      int rr = (r & 3) + 8 * (r >> 2) + 4 * l5;
      float v = accR[r] + bc;
      rb[(tm + tw + rr) * 1024 + col] = f2bf(v > 0.f ? v : 0.f);
    }
  }
  {
    int tok = tm + tw + l31;
    float eb = __expf(b2[tok & 2047]);
#pragma unroll
    for (int r = 0; r < 16; ++r) {
      int rr = (r & 3) + 8 * (r >> 2) + 4 * l5;
      int ch = n0 + cw + rr;
      vtb[ch * 4096 + tok] = f2bf((accV[r] + bv[ch]) * eb);
    }
  }
}

// ---------------- final GEMM: r3 config ------------------------------------
// 64x64 block, 4 waves 2x2, one 32x32 acc each, BK=128, simple 2-barrier,
// 32KB LDS, grid (16,64)=1024 blocks = 4/CU.
__global__ __launch_bounds__(256) void gemm_p(
    const unsigned short* __restrict__ A, const unsigned short* __restrict__ Bt,
    const float* __restrict__ bias, float* __restrict__ C) {
  __shared__ unsigned short As[64 * 128];
  __shared__ unsigned short Bs[64 * 128];
  const int tid = threadIdx.x;
  const int wv = tid >> 6, ln = tid & 63;
  const int l5 = ln >> 5, l31 = ln & 31;
  const int wm = (wv & 1) * 32, wn = (wv >> 1) * 32;
  const int tileM = blockIdx.y * 64, tileN = blockIdx.x * 64;
  const int srow = ln >> 4, pos = ln & 15;

  int aoff[8], boff[8];
#pragma unroll
  for (int kk = 0; kk < 8; ++kk) {
    int c = kk * 2 + l5;
    int p = ((c & 8) | ((c & 7) ^ (l31 & 7))) * 8;
    aoff[kk] = (wm + l31) * 128 + p;
    boff[kk] = (wn + l31) * 128 + p;
  }

  f32x16 acc;
#pragma unroll
  for (int i = 0; i < 16; ++i) acc[i] = 0.f;

  for (int k0 = 0; k0 < 1024; k0 += 128) {
    __syncthreads();
#pragma unroll
    for (int l = 0; l < 4; ++l) {
      int row = l * 16 + wv * 4 + srow;
      int cs = (pos & 8) | ((pos & 7) ^ (row & 7));
      gload_lds16(A + (tileM + row) * 1024 + k0 + cs * 8, &As[(l * 16 + wv * 4) * 128]);
      gload_lds16(Bt + (tileN + row) * 1024 + k0 + cs * 8, &Bs[(l * 16 + wv * 4) * 128]);
    }
    __syncthreads();
#pragma unroll
    for (int kk = 0; kk < 8; ++kk) {
      bf16x8 af  = *(const bf16x8*)&As[aoff[kk]];
      bf16x8 bfr = *(const bf16x8*)&Bs[boff[kk]];
      acc = __builtin_amdgcn_mfma_f32_32x32x16_bf16(af, bfr, acc, 0, 0, 0);
    }
  }
#pragma unroll
  for (int r = 0; r < 16; ++r) {
    int rr = (r & 3) + 8 * (r >> 2) + 4 * l5;
    int row = tileM + wm + rr;
    int col = tileN + wn + l31;
    C[row * 1024 + col] = acc[r] + bias[col];
  }
}

// ---------------- fused synthesizer attention: in-reg P, KVBLK=128 ----------
// r11 structure with W2 SINGLE-buffered: LDS 64KB -> 48KB unlocks 3 blocks/CU
// (r11 counters: LDS was the occupancy binder at 2 blocks/CU = 2 waves/SIMD;
// VGPR 128 allows 3).  Per interval: vmcnt(0)+barrier (tiles resident) ->
// read w2f/eb fragments -> lgkmcnt(0)+barrier#2 (W2s read-complete, no memory
// drain attached) -> stage W2(jt+1)+V(jt+1) -> compute.  V stays
// double-buffered; per-wave math identical to r11's verified path.
__global__ __launch_bounds__(256, 3) void attn(
    const unsigned short* __restrict__ r, const unsigned short* __restrict__ w2t,
    const unsigned short* __restrict__ vt, const unsigned short* __restrict__ ebj,
    unsigned short* __restrict__ y) {
  __shared__ unsigned short W2s[128 * 64];      // 16KB, single-buffered
  __shared__ unsigned short Vs[2][64 * 128];    // 32KB, double-buffered

  const int tid = threadIdx.x;
  const int wv = tid >> 6, ln = tid & 63;
  const int quad = ln >> 4, lq = ln & 15;
  const int bh = blockIdx.x, b = bh >> 4, h = bh & 15;
  const int q = blockIdx.y;
  const int p = (q < 8) ? q : 23 - q;             // pair (p, 31-p)
  const int ta = p, tb = 31 - p;
  const int t0a = ta * 64, t0b = tb * 64;
  const int diagA = t0a >> 7;                     // tile-a's diagonal interval
  const int NB = (t0b >> 7) + 1;                  // interval count (9..16)
  const int rowL = ln >> 3;
  const int kc = (((ln & 7) ^ rowL) & 7) * 8;     // W2 staging src chunk
  // V staging: lane covers (row = l*16 + wv*4 + (ln>>4), pos = ln&15)
  const int vrow7 = (wv * 4 + (ln >> 4)) & 7;
  const int vpos = ln & 15;
  const int vc = (((vpos & 8) | ((vpos & 7) ^ vrow7))) * 8;
  // fragment chunk offsets
  const int sx = lq & 7;
  int vko[4];
#pragma unroll
  for (int ks = 0; ks < 4; ++ks) {
    int c = ks * 4 + quad;
    vko[ks] = ((c & 8) | ((c & 7) ^ sx)) * 8;
  }

  // R B-fragments for both tiles (L2-hot)
  bf16x8 ra[2][2];
  {
    const unsigned short* base = r + (b * 2048 + wv * 16 + lq) * 1024 + h * 64 + quad * 8;
    ra[0][0] = *(const bf16x8*)(base + t0a * 1024);
    ra[0][1] = *(const bf16x8*)(base + t0a * 1024 + 32);
    ra[1][0] = *(const bf16x8*)(base + t0b * 1024);
    ra[1][1] = *(const bf16x8*)(base + t0b * 1024 + 32);
  }

  f32x4 accY[2][4];
  f32x4 accL[2];
  const f32x4 zf = {0.f, 0.f, 0.f, 0.f};
#pragma unroll
  for (int s = 0; s < 2; ++s) {
    accL[s] = zf;
#pragma unroll
    for (int nd = 0; nd < 4; ++nd) accY[s][nd] = zf;
  }

  auto stageW2 = [&](int jt) {
    int j0 = jt * 128;
#pragma unroll
    for (int l = 0; l < 4; ++l) {
      int row = l * 32 + wv * 8 + rowL;
      gload_lds16(w2t + (j0 + row) * 64 + kc, &W2s[(l * 32 + wv * 8) * 64]);
    }
  };
  auto stageV = [&](int jt, int bi) {
    int j0 = jt * 128;
#pragma unroll
    for (int l = 0; l < 4; ++l) {
      int row = l * 16 + wv * 4 + (ln >> 4);
      gload_lds16(vt + (h * 64 + row) * 4096 + b * 2048 + j0 + vc,
                  &Vs[bi][(l * 16 + wv * 4) * 128]);
    }
  };

#define TILE(S, T0, TTJ)                                                        \
    {                                                                           \
      f32x4 sv[8];                                                              \
      _Pragma("unroll") for (int ni = 0; ni < 8; ++ni) {                        \
        sv[ni] = __builtin_amdgcn_mfma_f32_16x16x32_bf16(w2f[ni][0], ra[S][0], zf, 0, 0, 0); \
        sv[ni] = __builtin_amdgcn_mfma_f32_16x16x32_bf16(w2f[ni][1], ra[S][1], sv[ni], 0, 0, 0); \
      }                                                                         \
      const bool diag = (jt == (TTJ));                                          \
      const int tl = (T0) + wv * 16 + lq;                                       \
      _Pragma("unroll") for (int ni = 0; ni < 8; ++ni)                          \
        _Pragma("unroll") for (int rg = 0; rg < 4; ++rg) {                      \
          float pe = __expf(sv[ni][rg]);                                        \
          if (diag) {                                                           \
            int j = j0 + ni * 16 + quad * 4 + rg;                               \
            pe = (j <= tl) ? pe : 0.f;                                          \
          }                                                                     \
          sv[ni][rg] = pe;                                                      \
        }                                                                       \
      bf16x8 pa[4];                                                             \
      _Pragma("unroll") for (int s2 = 0; s2 < 4; ++s2) {                        \
        union { unsigned u[4]; bf16x8 v; } ku;                                  \
        _Pragma("unroll") for (int pr = 0; pr < 2; ++pr) {                      \
          unsigned a0 = cvtpk(sv[2 * s2][2 * pr], sv[2 * s2][2 * pr + 1]);      \
          unsigned b0 = cvtpk(sv[2 * s2 + 1][2 * pr], sv[2 * s2 + 1][2 * pr + 1]); \
          asm("v_permlane32_swap_b32 %0, %1" : "+v"(a0), "+v"(b0));             \
          asm("v_permlane16_swap_b32 %0, %1" : "+v"(a0), "+v"(b0));             \
          ku.u[pr] = a0; ku.u[2 + pr] = b0;                                     \
        }                                                                       \
        pa[s2] = ku.v;                                                          \
      }                                                                         \
      _Pragma("unroll") for (int nd = 0; nd < 4; ++nd)                          \
        _Pragma("unroll") for (int ks = 0; ks < 4; ++ks) {                      \
          bf16x8 bb = *(const bf16x8*)&Vs[cb][(nd * 16 + lq) * 128 + vko[ks]];  \
          accY[S][nd] = __builtin_amdgcn_mfma_f32_16x16x32_bf16(pa[ks], bb, accY[S][nd], 0, 0, 0); \
        }                                                                       \
      _Pragma("unroll") for (int ks = 0; ks < 4; ++ks)                          \
        accL[S] = __builtin_amdgcn_mfma_f32_16x16x32_bf16(pa[ks], eb[ks], accL[S], 0, 0, 0); \
    }

#define WRITEOUT(S, T0)                                                         \
    {                                                                           \
      float inv[4];                                                             \
      _Pragma("unroll") for (int rg = 0; rg < 4; ++rg)                          \
        inv[rg] = __builtin_amdgcn_rcpf(accL[S][rg]);                           \
      _Pragma("unroll") for (int nd = 0; nd < 4; ++nd)                          \
        _Pragma("unroll") for (int rg = 0; rg < 4; ++rg) {                      \
          int t = (T0) + wv * 16 + quad * 4 + rg;                               \
          y[(b * 2048 + t) * 1024 + h * 64 + nd * 16 + lq] =                    \
              f2bf(accY[S][nd][rg] * inv[rg]);                                  \
        }                                                                       \
    }

  stageW2(0);
  stageV(0, 0);
  for (int jt = 0; jt < NB; ++jt) {
    const int cb = jt & 1;
    asm volatile("s_waitcnt vmcnt(0)" ::: "memory");   // W2(jt)+V(jt) DMAs landed
    __builtin_amdgcn_s_barrier();                       // ...for every wave
    const int j0 = jt * 128;

    // read per-interval fragments from W2s (single buffer) + ebj
    bf16x8 eb[4];
#pragma unroll
    for (int ks = 0; ks < 4; ++ks)
      eb[ks] = *(const bf16x8*)&ebj[j0 + ks * 32 + quad * 8];
    bf16x8 w2f[8][2];
#pragma unroll
    for (int ni = 0; ni < 8; ++ni) {
      w2f[ni][0] = *(const bf16x8*)&W2s[(ni * 16 + lq) * 64 + ((0 * 4 + quad) ^ sx) * 8];
      w2f[ni][1] = *(const bf16x8*)&W2s[(ni * 16 + lq) * 64 + ((1 * 4 + quad) ^ sx) * 8];
    }
    asm volatile("s_waitcnt lgkmcnt(0)" ::: "memory");  // this wave's W2s reads done
    __builtin_amdgcn_sched_barrier(0);
    __builtin_amdgcn_s_barrier();                       // all waves done reading W2s

    if (jt + 1 < NB) { stageW2(jt + 1); stageV(jt + 1, cb ^ 1); }

    if (jt <= diagA) TILE(0, t0a, diagA);
    TILE(1, t0b, NB - 1);
    if (jt == diagA) WRITEOUT(0, t0a);
  }
  WRITEOUT(1, t0b);
#undef TILE
#undef WRITEOUT
}

// ---------------- launch ----------------
extern "C" void kernel_launch(void* const* d_in, const int* in_sizes, int n_in,
                              void* d_out, int out_size, void* d_ws, size_t ws_size,
                              hipStream_t stream) {
  const float* x  = (const float*)d_in[0];
  const float* W1 = (const float*)d_in[1];
  const float* b1 = (const float*)d_in[2];
  const float* w2 = (const float*)d_in[3];
  const float* b2 = (const float*)d_in[4];
  const float* Wv = (const float*)d_in[5];
  const float* bv = (const float*)d_in[6];
  const float* Wp = (const float*)d_in[7];
  const float* bp = (const float*)d_in[8];

  unsigned short* ws  = (unsigned short*)d_ws;
  unsigned short* xb   = ws;                 // 4096x1024 bf16
  unsigned short* W1b  = ws + 4194304;       // 1024x1024
  unsigned short* Wvb  = ws + 5242880;       // 1024x1024
  unsigned short* Wpb  = ws + 6291456;       // 1024x1024
  unsigned short* w2t  = ws + 7340032;       // 2048x64
  unsigned short* rb   = ws + 7471104;       // 4096x1024
  unsigned short* vt   = ws + 11665408;      // 1024x4096
  unsigned short* yb   = ws + 15859712;      // 4096x1024 bf16
  unsigned short* ebjb = ws + 20054016;      // 2048 bf16

  prep<<<7298, 256, 0, stream>>>(x, W1, Wv, Wp, w2, b2, xb, W1b, Wvb, Wpb, w2t, ebjb);
  gemm_rv<<<dim3(64, 16), 256, 0, stream>>>(xb, W1b, Wvb, b1, bv, b2, rb, vt);
  attn<<<dim3(32, 16), 256, 0, stream>>>(rb, w2t, vt, ebjb, yb);
  gemm_p<<<dim3(16, 64), 256, 0, stream>>>(yb, Wpb, bp, (float*)d_out);
}

// Round 13
// 157.597 us; speedup vs baseline: 1.6302x; 1.6302x over previous
//
#include <hip/hip_runtime.h>

typedef __bf16 bf16x8 __attribute__((ext_vector_type(8)));
typedef float f32x4 __attribute__((ext_vector_type(4)));
typedef float f32x16 __attribute__((ext_vector_type(16)));

__device__ __forceinline__ unsigned short f2bf(float f) {
  union { float f; unsigned u; } v; v.f = f;
  unsigned u = v.u;
  return (unsigned short)((u + 0x7fffu + ((u >> 16) & 1u)) >> 16);  // RNE
}
__device__ __forceinline__ void gload_lds16(const void* g, void* l) {
  __builtin_amdgcn_global_load_lds(
      (const __attribute__((address_space(1))) unsigned int*)g,
      (__attribute__((address_space(3))) unsigned int*)l, 16, 0, 0);
}
__device__ __forceinline__ unsigned cvtpk(float lo, float hi) {
  unsigned r;
  asm("v_cvt_pk_bf16_f32 %0, %1, %2" : "=v"(r) : "v"(lo), "v"(hi));
  return r;
}
// bulk f32->bf16 x4 via hardware cvt_pk (RNE, same rounding as f2bf)
__device__ __forceinline__ void cvt4(const float* __restrict__ s,
                                     unsigned short* __restrict__ d, int u) {
  f32x4 v = ((const f32x4*)s)[u];
  unsigned lo = cvtpk(v[0], v[1]);
  unsigned hi = cvtpk(v[2], v[3]);
  unsigned long long o = ((unsigned long long)hi << 32) | (unsigned long long)lo;
  ((unsigned long long*)d)[u] = o;
}

// LDS tile swizzle (128B rows): row r, 16B-chunk c stored at position c^(r&7).
// Staging lane fetches global chunk (ln&7)^(ln>>3); reads XOR chunk with r&7.
// For 256B rows: chunk c (0..15) at position (c&8)|((c&7)^(r&7)).

// ---------------- prep: f32->bf16 conversions + ebj, one launch -------------
__global__ void prep(const float* __restrict__ x, const float* __restrict__ W1,
                     const float* __restrict__ Wv, const float* __restrict__ Wp,
                     const float* __restrict__ w2, const float* __restrict__ b2,
                     unsigned short* __restrict__ xb, unsigned short* __restrict__ W1b,
                     unsigned short* __restrict__ Wvb, unsigned short* __restrict__ Wpb,
                     unsigned short* __restrict__ w2t, unsigned short* __restrict__ ebj) {
  int u = blockIdx.x * 256 + threadIdx.x;
  if (u < 1048576) { cvt4(x, xb, u); return; }
  u -= 1048576;
  if (u < 262144) { cvt4(W1, W1b, u); return; }
  u -= 262144;
  if (u < 262144) { cvt4(Wv, Wvb, u); return; }
  u -= 262144;
  if (u < 262144) { cvt4(Wp, Wpb, u); return; }
  u -= 262144;
  if (u < 32768) {
    // w2 (64,2048) f32 -> w2t (2048,64) bf16
    int j = u >> 4, d4 = (u & 15) * 4;
    union { unsigned short s[4]; unsigned long long x; } o;
#pragma unroll
    for (int i = 0; i < 4; ++i) o.s[i] = f2bf(w2[(d4 + i) * 2048 + j]);
    ((unsigned long long*)w2t)[u] = o.x;
    return;
  }
  u -= 32768;
  // ebj = bf16(exp(b2)), 2048 elems in 512 x4-units
  union { unsigned short s[4]; unsigned long long x; } o;
#pragma unroll
  for (int i = 0; i < 4; ++i) o.s[i] = f2bf(__expf(b2[u * 4 + i]));
  ((unsigned long long*)ebj)[u] = o.x;
}

// ---------------- fused r & vt GEMM: r3 config (best measured total) --------
// 64x64 tile, 4 waves, 32x32 MFMA, shared-X fragments, simple 2-barrier loop,
// 24KB LDS, grid (64,16)=1024 blocks = 4/CU.
__global__ __launch_bounds__(256) void gemm_rv(
    const unsigned short* __restrict__ xb, const unsigned short* __restrict__ W1b,
    const unsigned short* __restrict__ Wvb, const float* __restrict__ b1,
    const float* __restrict__ bv, const float* __restrict__ b2,
    unsigned short* __restrict__ rb, unsigned short* __restrict__ vtb) {
  __shared__ unsigned short Xs[64 * 64];
  __shared__ unsigned short W1s[64 * 64];
  __shared__ unsigned short Wvs[64 * 64];
  const int tm = blockIdx.x * 64, n0 = blockIdx.y * 64;
  const int tid = threadIdx.x;
  const int wv = tid >> 6, ln = tid & 63;
  const int l5 = ln >> 5, l31 = ln & 31;
  const int tw = (wv & 1) * 32;      // token base within tile
  const int cw = (wv >> 1) * 32;     // chan base within tile
  const int rowL = ln >> 3;
  const int kc = (((ln & 7) ^ rowL) & 7) * 8;

  int xoff[4], woff[4];
#pragma unroll
  for (int kk = 0; kk < 4; ++kk) {
    int c = kk * 2 + l5;
    int p = (c ^ (l31 & 7)) * 8;
    xoff[kk] = (tw + l31) * 64 + p;
    woff[kk] = (cw + l31) * 64 + p;
  }

  f32x16 accR, accV;
#pragma unroll
  for (int i = 0; i < 16; ++i) { accR[i] = 0.f; accV[i] = 0.f; }

  for (int k0 = 0; k0 < 1024; k0 += 64) {
    __syncthreads();
#pragma unroll
    for (int l = 0; l < 2; ++l) {
      int row = l * 32 + wv * 8 + rowL;
      gload_lds16(xb + (tm + row) * 1024 + k0 + kc, &Xs[l * 2048 + wv * 512]);
      gload_lds16(W1b + (n0 + row) * 1024 + k0 + kc, &W1s[l * 2048 + wv * 512]);
      gload_lds16(Wvb + (n0 + row) * 1024 + k0 + kc, &Wvs[l * 2048 + wv * 512]);
    }
    __syncthreads();
#pragma unroll
    for (int kk = 0; kk < 4; ++kk) {
      bf16x8 xa  = *(const bf16x8*)&Xs[xoff[kk]];
      bf16x8 w1f = *(const bf16x8*)&W1s[woff[kk]];
      bf16x8 wvf = *(const bf16x8*)&Wvs[woff[kk]];
      accR = __builtin_amdgcn_mfma_f32_32x32x16_bf16(xa, w1f, accR, 0, 0, 0);
      accV = __builtin_amdgcn_mfma_f32_32x32x16_bf16(wvf, xa, accV, 0, 0, 0);
    }
  }
  {
    int col = n0 + cw + l31;
    float bc = b1[col];
#pragma unroll
    for (int r = 0; r < 16; ++r) {
      int rr = (r & 3) + 8 * (r >> 2) + 4 * l5;
      float v = accR[r] + bc;
      rb[(tm + tw + rr) * 1024 + col] = f2bf(v > 0.f ? v : 0.f);
    }
  }
  {
    int tok = tm + tw + l31;
    float eb = __expf(b2[tok & 2047]);
#pragma unroll
    for (int r = 0; r < 16; ++r) {
      int rr = (r & 3) + 8 * (r >> 2) + 4 * l5;
      int ch = n0 + cw + rr;
      vtb[ch * 4096 + tok] = f2bf((accV[r] + bv[ch]) * eb);
    }
  }
}

// ---------------- final GEMM: r3 config ------------------------------------
// 64x64 block, 4 waves 2x2, one 32x32 acc each, BK=128, simple 2-barrier,
// 32KB LDS, grid (16,64)=1024 blocks = 4/CU.
__global__ __launch_bounds__(256) void gemm_p(
    const unsigned short* __restrict__ A, const unsigned short* __restrict__ Bt,
    const float* __restrict__ bias, float* __restrict__ C) {
  __shared__ unsigned short As[64 * 128];
  __shared__ unsigned short Bs[64 * 128];
  const int tid = threadIdx.x;
  const int wv = tid >> 6, ln = tid & 63;
  const int l5 = ln >> 5, l31 = ln & 31;
  const int wm = (wv & 1) * 32, wn = (wv >> 1) * 32;
  const int tileM = blockIdx.y * 64, tileN = blockIdx.x * 64;
  const int srow = ln >> 4, pos = ln & 15;

  int aoff[8], boff[8];
#pragma unroll
  for (int kk = 0; kk < 8; ++kk) {
    int c = kk * 2 + l5;
    int p = ((c & 8) | ((c & 7) ^ (l31 & 7))) * 8;
    aoff[kk] = (wm + l31) * 128 + p;
    boff[kk] = (wn + l31) * 128 + p;
  }

  f32x16 acc;
#pragma unroll
  for (int i = 0; i < 16; ++i) acc[i] = 0.f;

  for (int k0 = 0; k0 < 1024; k0 += 128) {
    __syncthreads();
#pragma unroll
    for (int l = 0; l < 4; ++l) {
      int row = l * 16 + wv * 4 + srow;
      int cs = (pos & 8) | ((pos & 7) ^ (row & 7));
      gload_lds16(A + (tileM + row) * 1024 + k0 + cs * 8, &As[(l * 16 + wv * 4) * 128]);
      gload_lds16(Bt + (tileN + row) * 1024 + k0 + cs * 8, &Bs[(l * 16 + wv * 4) * 128]);
    }
    __syncthreads();
#pragma unroll
    for (int kk = 0; kk < 8; ++kk) {
      bf16x8 af  = *(const bf16x8*)&As[aoff[kk]];
      bf16x8 bfr = *(const bf16x8*)&Bs[boff[kk]];
      acc = __builtin_amdgcn_mfma_f32_32x32x16_bf16(af, bfr, acc, 0, 0, 0);
    }
  }
#pragma unroll
  for (int r = 0; r < 16; ++r) {
    int rr = (r & 3) + 8 * (r >> 2) + 4 * l5;
    int row = tileM + wm + rr;
    int col = tileN + wn + l31;
    C[row * 1024 + col] = acc[r] + bias[col];
  }
}

// -------- fused synthesizer attention: unpaired KVBLK=128, W2 single-buf ----
// Synthesis of the three failed occupancy attempts:
//   - UNPAIRED (grid (32,32)=1024 blocks) so >2 blocks/CU can exist at all
//     (the pair grid of 512 was a hard 2/CU cap -- r12's premise was void).
//   - KVBLK=128 keeps staging overhead at +36% (272 vs 200 stage-intervals/bh),
//     not r9's +61% at KVBLK=64.
//   - W2s SINGLE-buffered (16KB) + Vs double (32KB) = 48KB -> 3 blocks/CU
//     (12 waves/CU, +50% TLP on the latency-bound interval r11's counters
//     pinned: MfmaUtil 16.5 / VALU 30 / occ 19).
//   - No spills (r12's failure): unpairing halves the live set (one accY[4],
//     one ra pair, one sv/pa generation); W2 fragments are read IN the S loop
//     and die into their MFMAs immediately.
// Schedule per interval: vmcnt(0)+barrier (tiles resident) -> S loop
// (ds_read w2f -> 2 MFMA, per ni) -> lgkmcnt(0)+sched_barrier+barrier#2
// (all waves done reading W2s; no memory drain attached) -> stage W2/V(jt+1)
// -> exp/mask -> pack -> PV from Vs[cb].  Per-wave math identical to r11.
__global__ __launch_bounds__(256, 3) void attn(
    const unsigned short* __restrict__ r, const unsigned short* __restrict__ w2t,
    const unsigned short* __restrict__ vt, const unsigned short* __restrict__ ebj,
    unsigned short* __restrict__ y) {
  __shared__ unsigned short W2s[128 * 64];      // 16KB, single-buffered
  __shared__ unsigned short Vs[2][64 * 128];    // 32KB, double-buffered

  const int tid = threadIdx.x;
  const int wv = tid >> 6, ln = tid & 63;
  const int quad = ln >> 4, lq = ln & 15;
  const int bh = blockIdx.x, b = bh >> 4, h = bh & 15;
  const int q = 31 - blockIdx.y;                  // tile 0..31, heavy first
  const int t0 = q * 64;
  const int NB = (t0 >> 7) + 1;                   // 128-wide j-intervals
  const int rowL = ln >> 3;
  const int kc = (((ln & 7) ^ rowL) & 7) * 8;     // W2 staging src chunk
  // V staging: lane covers (row = l*16 + wv*4 + (ln>>4), pos = ln&15)
  const int vrow7 = (wv * 4 + (ln >> 4)) & 7;
  const int vpos = ln & 15;
  const int vc = (((vpos & 8) | ((vpos & 7) ^ vrow7))) * 8;
  // fragment chunk offsets
  const int sx = lq & 7;
  const int ko0 = (quad ^ sx) * 8, ko1 = ((4 + quad) ^ sx) * 8;  // W2s 128B rows
  int vko[4];
#pragma unroll
  for (int ks = 0; ks < 4; ++ks) {
    int c = ks * 4 + quad;
    vko[ks] = ((c & 8) | ((c & 7) ^ sx)) * 8;     // Vs 256B rows
  }

  // R B-fragments: this wave's 16 tokens (L2-hot)
  bf16x8 ra0, ra1;
  {
    const unsigned short* base =
        r + (b * 2048 + t0 + wv * 16 + lq) * 1024 + h * 64 + quad * 8;
    ra0 = *(const bf16x8*)(base);
    ra1 = *(const bf16x8*)(base + 32);
  }

  f32x4 accY[4];
  f32x4 accL;
  const f32x4 zf = {0.f, 0.f, 0.f, 0.f};
  accL = zf;
#pragma unroll
  for (int nd = 0; nd < 4; ++nd) accY[nd] = zf;

  auto stageW2 = [&](int jt) {
    int j0 = jt * 128;
#pragma unroll
    for (int l = 0; l < 4; ++l) {
      int row = l * 32 + wv * 8 + rowL;
      gload_lds16(w2t + (j0 + row) * 64 + kc, &W2s[(l * 32 + wv * 8) * 64]);
    }
  };
  auto stageV = [&](int jt, int bi) {
    int j0 = jt * 128;
#pragma unroll
    for (int l = 0; l < 4; ++l) {
      int row = l * 16 + wv * 4 + (ln >> 4);
      gload_lds16(vt + (h * 64 + row) * 4096 + b * 2048 + j0 + vc,
                  &Vs[bi][(l * 16 + wv * 4) * 128]);
    }
  };

  stageW2(0);
  stageV(0, 0);
  for (int jt = 0; jt < NB; ++jt) {
    const int cb = jt & 1;
    asm volatile("s_waitcnt vmcnt(0)" ::: "memory");  // W2(jt)+V(jt) DMAs landed
    __builtin_amdgcn_s_barrier();                      // ...for every wave
    const int j0 = jt * 128;

    // ---- S phase: read w2f pair per ni, consume immediately (low live set)
    f32x4 sv[8];
#pragma unroll
    for (int ni = 0; ni < 8; ++ni) {
      bf16x8 w2a = *(const bf16x8*)&W2s[(ni * 16 + lq) * 64 + ko0];
      bf16x8 w2b = *(const bf16x8*)&W2s[(ni * 16 + lq) * 64 + ko1];
      sv[ni] = __builtin_amdgcn_mfma_f32_16x16x32_bf16(w2a, ra0, zf, 0, 0, 0);
      sv[ni] = __builtin_amdgcn_mfma_f32_16x16x32_bf16(w2b, ra1, sv[ni], 0, 0, 0);
    }
    // ebj fragments (global, L2-hot)
    bf16x8 eb[4];
#pragma unroll
    for (int ks = 0; ks < 4; ++ks)
      eb[ks] = *(const bf16x8*)&ebj[j0 + ks * 32 + quad * 8];

    asm volatile("s_waitcnt lgkmcnt(0)" ::: "memory"); // this wave's W2s reads done
    __builtin_amdgcn_sched_barrier(0);
    __builtin_amdgcn_s_barrier();                      // all waves done reading W2s

    if (jt + 1 < NB) { stageW2(jt + 1); stageV(jt + 1, cb ^ 1); }

    // ---- exp + causal mask ----
    const bool diag = (jt == NB - 1);
    const int tl = t0 + wv * 16 + lq;
#pragma unroll
    for (int ni = 0; ni < 8; ++ni)
#pragma unroll
      for (int rg = 0; rg < 4; ++rg) {
        float pe = __expf(sv[ni][rg]);
        if (diag) {
          int j = j0 + ni * 16 + quad * 4 + rg;
          pe = (j <= tl) ? pe : 0.f;
        }
        sv[ni][rg] = pe;
      }

    // ---- pack P to A-fragments (cvt_pk + permlane quad exchange) ----
    bf16x8 pa[4];
#pragma unroll
    for (int s2 = 0; s2 < 4; ++s2) {
      union { unsigned u[4]; bf16x8 v; } ku;
#pragma unroll
      for (int pr = 0; pr < 2; ++pr) {
        unsigned a0 = cvtpk(sv[2 * s2][2 * pr], sv[2 * s2][2 * pr + 1]);
        unsigned b0 = cvtpk(sv[2 * s2 + 1][2 * pr], sv[2 * s2 + 1][2 * pr + 1]);
        asm("v_permlane32_swap_b32 %0, %1" : "+v"(a0), "+v"(b0));
        asm("v_permlane16_swap_b32 %0, %1" : "+v"(a0), "+v"(b0));
        ku.u[pr] = a0; ku.u[2 + pr] = b0;
      }
      pa[s2] = ku.v;
    }

    // ---- PV + L from Vs[cb] (double-buffered; staging went to cb^1) ----
#pragma unroll
    for (int nd = 0; nd < 4; ++nd)
#pragma unroll
      for (int ks = 0; ks < 4; ++ks) {
        bf16x8 bb = *(const bf16x8*)&Vs[cb][(nd * 16 + lq) * 128 + vko[ks]];
        accY[nd] = __builtin_amdgcn_mfma_f32_16x16x32_bf16(pa[ks], bb, accY[nd], 0, 0, 0);
      }
#pragma unroll
    for (int ks = 0; ks < 4; ++ks)
      accL = __builtin_amdgcn_mfma_f32_16x16x32_bf16(pa[ks], eb[ks], accL, 0, 0, 0);
  }

  // ---- writeout: this wave's 16 tokens x 64 chans ----
  {
    float inv[4];
#pragma unroll
    for (int rg = 0; rg < 4; ++rg) inv[rg] = __builtin_amdgcn_rcpf(accL[rg]);
#pragma unroll
    for (int nd = 0; nd < 4; ++nd)
#pragma unroll
      for (int rg = 0; rg < 4; ++rg) {
        int t = t0 + wv * 16 + quad * 4 + rg;
        y[(b * 2048 + t) * 1024 + h * 64 + nd * 16 + lq] =
            f2bf(accY[nd][rg] * inv[rg]);
      }
  }
}

// ---------------- launch ----------------
extern "C" void kernel_launch(void* const* d_in, const int* in_sizes, int n_in,
                              void* d_out, int out_size, void* d_ws, size_t ws_size,
                              hipStream_t stream) {
  const float* x  = (const float*)d_in[0];
  const float* W1 = (const float*)d_in[1];
  const float* b1 = (const float*)d_in[2];
  const float* w2 = (const float*)d_in[3];
  const float* b2 = (const float*)d_in[4];
  const float* Wv = (const float*)d_in[5];
  const float* bv = (const float*)d_in[6];
  const float* Wp = (const float*)d_in[7];
  const float* bp = (const float*)d_in[8];

  unsigned short* ws  = (unsigned short*)d_ws;
  unsigned short* xb   = ws;                 // 4096x1024 bf16
  unsigned short* W1b  = ws + 4194304;       // 1024x1024
  unsigned short* Wvb  = ws + 5242880;       // 1024x1024
  unsigned short* Wpb  = ws + 6291456;       // 1024x1024
  unsigned short* w2t  = ws + 7340032;       // 2048x64
  unsigned short* rb   = ws + 7471104;       // 4096x1024
  unsigned short* vt   = ws + 11665408;      // 1024x4096
  unsigned short* yb   = ws + 15859712;      // 4096x1024 bf16
  unsigned short* ebjb = ws + 20054016;      // 2048 bf16

  prep<<<7298, 256, 0, stream>>>(x, W1, Wv, Wp, w2, b2, xb, W1b, Wvb, Wpb, w2t, ebjb);
  gemm_rv<<<dim3(64, 16), 256, 0, stream>>>(xb, W1b, Wvb, b1, bv, b2, rb, vt);
  attn<<<dim3(32, 32), 256, 0, stream>>>(rb, w2t, vt, ebjb, yb);
  gemm_p<<<dim3(16, 64), 256, 0, stream>>>(yb, Wpb, bp, (float*)d_out);
}